// Round 1
// 60.752 us; speedup vs baseline: 1.0102x; 1.0102x over previous
//
#include <hip/hip_runtime.h>
#include <math.h>

#define SIGMA_MAJORANT 0.1f

// atan(q)/pi for q in [0,1]; minimax coefficients pre-divided by pi.
// Base poly |err| ~1e-6 rad -> ~3e-7 in grid units, negligible vs tolerance.
__device__ __forceinline__ float atan_over_pi(float q) {
    const float q2 = q * q;
    float r = -0.0037310f;
    r = fmaf(r, q2, 0.0167600f);
    r = fmaf(r, q2, -0.0370617f);
    r = fmaf(r, q2, 0.0616068f);
    r = fmaf(r, q2, -0.1058773f);
    r = fmaf(r, q2, 0.3183026f);
    return q * r;
}

// acos(u) for u in [0,1]: A&S 4.4.46, sqrt(1-u)*P7(u), |err| <= 2e-8 rad.
__device__ __forceinline__ float acos_core(float u) {
    float p = -0.0012624911f;
    p = fmaf(p, u, 0.0066700901f);
    p = fmaf(p, u, -0.0170881256f);
    p = fmaf(p, u, 0.0308918810f);
    p = fmaf(p, u, -0.0501743046f);
    p = fmaf(p, u, 0.0889789874f);
    p = fmaf(p, u, -0.2145988016f);
    p = fmaf(p, u, 1.5707963050f);
    return sqrtf(1.0f - u) * p;
}

// env_map: [1,3,16,32] -> env[c*H*W + y*W + x], H=16, W=32
__global__ __launch_bounds__(256) void nerf_env_kernel(
    const float* __restrict__ rays_o,
    const float* __restrict__ rays_d,
    const float* __restrict__ env,
    float* __restrict__ out,
    int N)
{
    int i = blockIdx.x * blockDim.x + threadIdx.x;
    if (i >= N) return;

    const float ox = rays_o[3 * i + 0];
    const float oy = rays_o[3 * i + 1];
    const float oz = rays_o[3 * i + 2];
    const float dx = rays_d[3 * i + 0];
    const float dy = rays_d[3 * i + 1];
    const float dz = rays_d[3 * i + 2];

    const float a = fmaf(dx, dx, fmaf(dy, dy, dz * dz));
    const float c = fmaf(ox, ox, fmaf(oy, oy, oz * oz)) - 1.0f;  // BOUND^2 = 1
    const float b = 2.0f * fmaf(ox, dx, fmaf(oy, dy, oz * dz));
    const float delta = fmaf(b, b, -4.0f * a * c);
    const float sd = sqrtf(delta > 0.0f ? delta : 1.0f);
    const float t = __fdividef(sd - b, 2.0f * a);
    const bool valid = (delta > 0.0f) && (t >= 0.0f);

    const float hx = fmaf(dx, t, ox);
    const float hy = fmaf(dy, t, oy);
    const float hz = fmaf(dz, t, oz);

    // ---- gy = atan2(hx, -hz) / pi  (grid y coordinate) ----
    const float as = fabsf(hx);
    const float ac = fabsf(hz);
    const float mx = fmaxf(as, ac);
    const float mn = fminf(as, ac);
    const float q = (mx > 0.0f) ? __fdividef(mn, mx) : 0.0f;  // 0/0 -> 0 (nan_to_num)
    float ang = atan_over_pi(q);           // angle/pi in [0, 0.25]
    if (as > ac)     ang = 0.5f - ang;     // |sin| > |cos|
    if (-hz < 0.0f)  ang = 1.0f - ang;     // cosine (= -hz) negative quadrant
    const float gy = copysignf(ang, hx);

    // ---- gx = (2/pi)*acos(clip(hy)) - 1  (grid x coordinate) ----
    float yc = fminf(fmaxf(hy, -1.0f + 1e-6f), 1.0f - 1e-6f);
    const float u = fabsf(yc);
    float g = fmaf(0.63661977f, acos_core(u), -1.0f);  // (2/pi)*acos(u) - 1, in [-1,0]
    const float gx = (yc >= 0.0f) ? g : -g;            // acos(-u) = pi - acos(u)

    // grid_sample, align_corners=False, padding zeros. H=16, W=32.
    // ix = ((gx+1)*W - 1)*0.5 = 16*gx + 15.5 ; iy = ((gy+1)*H - 1)*0.5 = 8*gy + 7.5
    const int H = 16, W = 32;
    const float ix = fmaf(16.0f, gx, 15.5f);
    const float iy = fmaf(8.0f, gy, 7.5f);
    const float ix0f = floorf(ix);
    const float iy0f = floorf(iy);
    const float wx1 = ix - ix0f;
    const float wy1 = iy - iy0f;
    const float wx0 = 1.0f - wx1;
    const float wy0 = 1.0f - wy1;

    const int ix0 = (int)ix0f;
    const int iy0 = (int)iy0f;
    const int ix1 = ix0 + 1;
    const int iy1 = iy0 + 1;

    const bool bx0 = (ix0 >= 0) && (ix0 <= W - 1);
    const bool bx1 = (ix1 >= 0) && (ix1 <= W - 1);
    const bool by0 = (iy0 >= 0) && (iy0 <= H - 1);
    const bool by1 = (iy1 >= 0) && (iy1 <= H - 1);

    const int cx0 = min(max(ix0, 0), W - 1);
    const int cx1 = min(max(ix1, 0), W - 1);
    const int cy0 = min(max(iy0, 0), H - 1);
    const int cy1 = min(max(iy1, 0), H - 1);

    const float w00 = wx0 * wy0 * ((bx0 && by0) ? 1.0f : 0.0f);
    const float w10 = wx1 * wy0 * ((bx1 && by0) ? 1.0f : 0.0f);
    const float w01 = wx0 * wy1 * ((bx0 && by1) ? 1.0f : 0.0f);
    const float w11 = wx1 * wy1 * ((bx1 && by1) ? 1.0f : 0.0f);

    const float atten = valid ? __expf(-SIGMA_MAJORANT * t) : 0.0f;

    #pragma unroll
    for (int ch = 0; ch < 3; ++ch) {
        const float* plane = env + ch * H * W;
        const float v = plane[cy0 * W + cx0] * w00
                      + plane[cy0 * W + cx1] * w10
                      + plane[cy1 * W + cx0] * w01
                      + plane[cy1 * W + cx1] * w11;
        out[3 * i + ch] = atten * __expf(v);
    }
}

extern "C" void kernel_launch(void* const* d_in, const int* in_sizes, int n_in,
                              void* d_out, int out_size, void* d_ws, size_t ws_size,
                              hipStream_t stream) {
    const float* rays_o = (const float*)d_in[0];
    const float* rays_d = (const float*)d_in[1];
    const float* env    = (const float*)d_in[2];
    float* out = (float*)d_out;
    const int N = in_sizes[0] / 3;  // 16384

    const int block = 256;
    const int grid = (N + block - 1) / block;
    nerf_env_kernel<<<grid, block, 0, stream>>>(rays_o, rays_d, env, out, N);
}